// Round 3
// baseline (660.140 us; speedup 1.0000x reference)
//
#include <hip/hip_runtime.h>

// Screened Poisson Jacobi-PCG, B=4, H=W=1024, fp32, fixed 13 iterations.
// Multi-kernel CG (proven structure), re-tiled for occupancy:
//   512 threads/block, 2 cols/thread (float2), 4 rows/block, 1024 blocks
//   -> 8192 waves total (vs 4096), up to 32 waves/CU, SAME memory traffic
//      (row-halo volume unchanged by the column split).
// Deferred-x lives in k_B now (it already holds p_t and alpha_t), so k_A
// needs only beta (2-way reduction) and never touches x.
// All dot-product partials in double => alpha/beta match the verified
// trajectory to ~1e-15.

#define HH 1024
#define WW 1024
#define BB 4
#define NQUAD 1024         // 4096 rows / 4
#define NT 512
#define NWAVES (NT/64)     // 8
#define EPS_PC 1e-8f
#define EPS_DOT 1e-12
#define NIT 13

union F2 { float2 v; float a[2]; };
__device__ __forceinline__ float2 zf2(){ return make_float2(0.f,0.f); }

__device__ __forceinline__ double block_reduce(double v, double* lds){
  __syncthreads();
  #pragma unroll
  for (int o = 32; o > 0; o >>= 1) v += __shfl_down(v, o, 64);
  if ((threadIdx.x & 63) == 0) lds[threadIdx.x >> 6] = v;
  __syncthreads();
  if (threadIdx.x == 0){
    double s = lds[0];
    #pragma unroll
    for (int w = 1; w < NWAVES; w++) s += lds[w];
    lds[0] = s;
  }
  __syncthreads();
  return lds[0];
}

__device__ __forceinline__ void block_reduce2(double& v1, double& v2, double* lds){
  __syncthreads();
  #pragma unroll
  for (int o = 32; o > 0; o >>= 1){
    v1 += __shfl_down(v1, o, 64);
    v2 += __shfl_down(v2, o, 64);
  }
  if ((threadIdx.x & 63) == 0){
    lds[threadIdx.x >> 6] = v1;
    lds[NWAVES + (threadIdx.x >> 6)] = v2;
  }
  __syncthreads();
  if (threadIdx.x == 0){
    double s1 = lds[0], s2 = lds[NWAVES];
    #pragma unroll
    for (int w = 1; w < NWAVES; w++){ s1 += lds[w]; s2 += lds[NWAVES + w]; }
    lds[0] = s1; lds[NWAVES] = s2;
  }
  __syncthreads();
  v1 = lds[0]; v2 = lds[NWAVES];
}

// XCD-contiguous swizzle (1024 = 8*128, bijective): XCD k gets a contiguous
// 128-quad row band so N/S halos are same-XCD L2 hits.
__device__ __forceinline__ int swz1024(int bid){ return ((bid & 7) << 7) + (bid >> 3); }

// ---- setup: b, Mdiag; r=b, p0=z=b/(Md+eps); rz0 partials ----
__global__ void __launch_bounds__(NT, 8) k_setup(
  const float* __restrict__ E, const float* __restrict__ DLp,
  const float* __restrict__ Mm, const float* __restrict__ lam,
  const float* __restrict__ mu, const float* __restrict__ wg,
  float* __restrict__ r, float* __restrict__ p0, float* __restrict__ Md,
  double* __restrict__ rz_parts)
{
  __shared__ double lds[2*NWAVES];
  const int tid = threadIdx.x;
  const int ln  = tid & 63;
  const int q = swz1024(blockIdx.x);
  const int row0 = q * 4;
  const int rr = row0 & (HH-1);
  const int c0 = tid * 2;
  const int base = row0 * WW + c0;
  const bool hasN = (rr > 0);
  const bool hasS = (rr < HH-4);

  F2 Em1, E0, wm1, w0;
  Em1.v = hasN ? *(const float2*)(E + base - WW)  : zf2();
  wm1.v = hasN ? *(const float2*)(wg + base - WW) : zf2();
  E0.v  = *(const float2*)(E + base);
  w0.v  = *(const float2*)(wg + base);

  double rz_acc = 0.0;
  #pragma unroll
  for (int k = 0; k < 4; k++){
    const int bk = base + k*WW;
    F2 Ep1, wp1, M4, L4, U4, D4;
    Ep1.v = (k < 3 || hasS) ? *(const float2*)(E + bk + WW) : zf2();
    wp1.v = (k < 3) ? *(const float2*)(wg + bk + WW) : zf2();
    M4.v = *(const float2*)(Mm + bk);
    L4.v = *(const float2*)(lam + bk);
    U4.v = *(const float2*)(mu + bk);
    D4.v = *(const float2*)(DLp + bk);

    float Ew  = __shfl_up(E0.a[1], 1, 64);
    float Ee  = __shfl_down(E0.a[0], 1, 64);
    float ww_ = __shfl_up(w0.a[1], 1, 64);
    if (ln == 0 && c0 > 0){ Ew = E[bk-1]; ww_ = wg[bk-1]; }
    if (ln == 63 && c0 + 2 < WW){ Ee = E[bk+2]; }

    const float ev[4]  = {Ew, E0.a[0], E0.a[1], Ee};
    const float wv3[3] = {ww_, w0.a[0], w0.a[1]};
    const bool rowHasN = (k > 0) || hasN;
    const bool rowHasS = (k < 3) || hasS;

    F2 r2, p2, m2;
    #pragma unroll
    for (int j = 0; j < 2; j++){
      const int c = c0 + j;
      const float cE = (c < WW-1) ? wv3[j+1] : 0.f;
      const float cW = (c > 0)    ? wv3[j]   : 0.f;
      const float cS = rowHasS ? wv3[j+1] : 0.f;
      const float cN = rowHasN ? wm1.a[j] : 0.f;
      const float u  = ev[j+1];
      const float me = U4.a[j] * M4.a[j];
      const float bv = cE*(ev[j+2]-u) - cW*(u-ev[j]) + cS*(Ep1.a[j]-u) - cN*(u-Em1.a[j])
                     + L4.a[j]*u + me*D4.a[j];
      const float mdv = L4.a[j] + me + cE + cW + cS + cN;
      const float z  = bv / (mdv + EPS_PC);
      r2.a[j] = bv; p2.a[j] = z; m2.a[j] = mdv;
      rz_acc += (double)bv * (double)z;
    }
    *(float2*)(r + bk)  = r2.v;
    *(float2*)(p0 + bk) = p2.v;
    *(float2*)(Md + bk) = m2.v;

    Em1 = E0; E0 = Ep1; wm1 = w0; w0 = wp1;   // shift window
  }
  const double s = block_reduce(rz_acc, lds);
  if (tid == 0) rz_parts[q] = s;
}

// ---- K_A(t): t==0: pAp_0 partials only.
//      t>=1: beta_t; p_t = r/(Md+eps) + beta*p_{t-1} (+halo recompute);
//            pAp_t partials. No x traffic (lives in k_B now). ----
__global__ void __launch_bounds__(NT, 6) k_A(
  const float* __restrict__ r, const float* __restrict__ Md,
  const float* __restrict__ p_in, float* __restrict__ p_out,
  const float* __restrict__ wg,
  const double* __restrict__ Rprev, const double* __restrict__ Rcur,
  double* __restrict__ Pout, int t)
{
  __shared__ double lds[2*NWAVES];
  const int tid = threadIdx.x;
  const int ln  = tid & 63;
  const int q = swz1024(blockIdx.x);
  const int row0 = q * 4;
  const int b = row0 >> 10;
  const int rr = row0 & (HH-1);
  const int c0 = tid * 2;
  const int base = row0 * WW + c0;
  const bool hasN = (rr > 0);
  const bool hasS = (rr < HH-4);

  F2 wgr[4], md[4], wgN;
  #pragma unroll
  for (int k = 0; k < 4; k++){
    wgr[k].v = *(const float2*)(wg + base + k*WW);
    md[k].v  = *(const float2*)(Md + base + k*WW);
  }
  wgN.v = hasN ? *(const float2*)(wg + base - WW) : zf2();

  float pn[6][2];                        // p_new rows rr-1 .. rr+4
  float beta = 0.f;
  if (t == 0){
    F2 tN, tS, tc[4];
    tN.v = hasN ? *(const float2*)(p_in + base - WW) : zf2();
    #pragma unroll
    for (int k = 0; k < 4; k++) tc[k].v = *(const float2*)(p_in + base + k*WW);
    tS.v = hasS ? *(const float2*)(p_in + base + 4*WW) : zf2();
    #pragma unroll
    for (int j = 0; j < 2; j++){
      pn[0][j] = tN.a[j]; pn[5][j] = tS.a[j];
      #pragma unroll
      for (int k = 0; k < 4; k++) pn[k+1][j] = tc[k].a[j];
    }
  } else {
    F2 rcN, pcN, mN, rcS, pcS, mS, rc[4], pc[4];
    if (hasN){
      rcN.v = *(const float2*)(r + base - WW);
      pcN.v = *(const float2*)(p_in + base - WW);
      mN.v  = *(const float2*)(Md + base - WW);
    } else { rcN.v = zf2(); pcN.v = zf2(); mN.v = zf2(); }
    #pragma unroll
    for (int k = 0; k < 4; k++){
      rc[k].v = *(const float2*)(r + base + k*WW);
      pc[k].v = *(const float2*)(p_in + base + k*WW);
    }
    if (hasS){
      rcS.v = *(const float2*)(r + base + 4*WW);
      pcS.v = *(const float2*)(p_in + base + 4*WW);
      mS.v  = *(const float2*)(Md + base + 4*WW);
    } else { rcS.v = zf2(); pcS.v = zf2(); mS.v = zf2(); }

    double v1 = (tid < 256) ? Rprev[(b << 8) + tid] : 0.0;
    double v2 = (tid < 256) ? Rcur [(b << 8) + tid] : 0.0;
    block_reduce2(v1, v2, lds);
    beta = (float)(v2 / (v1 + EPS_DOT));

    #pragma unroll
    for (int j = 0; j < 2; j++){
      pn[0][j] = hasN ? (rcN.a[j] / (mN.a[j] + EPS_PC) + beta * pcN.a[j]) : 0.f;
      pn[5][j] = hasS ? (rcS.a[j] / (mS.a[j] + EPS_PC) + beta * pcS.a[j]) : 0.f;
      #pragma unroll
      for (int k = 0; k < 4; k++)
        pn[k+1][j] = rc[k].a[j] / (md[k].a[j] + EPS_PC) + beta * pc[k].a[j];
    }
    #pragma unroll
    for (int k = 0; k < 4; k++){
      F2 o;
      #pragma unroll
      for (int j = 0; j < 2; j++) o.a[j] = pn[k+1][j];
      *(float2*)(p_out + base + k*WW) = o.v;
    }
  }

  // west/east exchange via shfl; wave-seam lanes recompute from global
  float pw[4], pe[4], ww[4];
  #pragma unroll
  for (int k = 0; k < 4; k++){
    pw[k] = __shfl_up(pn[k+1][1], 1, 64);
    pe[k] = __shfl_down(pn[k+1][0], 1, 64);
    ww[k] = __shfl_up(wgr[k].a[1], 1, 64);
  }
  if (ln == 0 && c0 > 0){
    #pragma unroll
    for (int k = 0; k < 4; k++){
      const int bk = base + k*WW;
      pw[k] = (t == 0) ? p_in[bk-1]
                       : r[bk-1] / (Md[bk-1] + EPS_PC) + beta * p_in[bk-1];
      ww[k] = wg[bk-1];
    }
  }
  if (ln == 63 && c0 + 2 < WW){
    #pragma unroll
    for (int k = 0; k < 4; k++){
      const int bk = base + k*WW;
      pe[k] = (t == 0) ? p_in[bk+2]
                       : r[bk+2] / (Md[bk+2] + EPS_PC) + beta * p_in[bk+2];
    }
  }

  double acc = 0.0;
  #pragma unroll
  for (int k = 0; k < 4; k++){
    const float pa[4]  = {pw[k], pn[k+1][0], pn[k+1][1], pe[k]};
    const float wv3[3] = {ww[k], wgr[k].a[0], wgr[k].a[1]};
    #pragma unroll
    for (int j = 0; j < 2; j++){
      const int c = c0 + j;
      const float cE = (c < WW-1) ? wv3[j+1] : 0.f;
      const float cW = (c > 0)    ? wv3[j]   : 0.f;
      const float cS = (k < 3) ? wgr[k].a[j] : (hasS ? wgr[3].a[j] : 0.f);
      const float cN = (k > 0) ? wgr[k-1].a[j] : (hasN ? wgN.a[j] : 0.f);
      const float ap = md[k].a[j]*pa[j+1] - cE*pa[j+2] - cW*pa[j]
                     - cS*pn[k+2][j] - cN*pn[k][j];
      acc += (double)ap * (double)pa[j+1];
    }
  }
  const double s = block_reduce(acc, lds);
  if (tid == 0) Pout[q] = s;
}

// ---- K_B(t), t=0..NIT-2: alpha_t; r -= alpha_t*(A p_t); rz_{t+1} partials;
//      deferred x: x += alpha_t * p_t (t==0: fresh write). ----
__global__ void __launch_bounds__(NT, 8) k_B(
  float* __restrict__ r, const float* __restrict__ p,
  const float* __restrict__ wg, const float* __restrict__ Md,
  float* __restrict__ x,
  const double* __restrict__ Rcur, const double* __restrict__ Pcur,
  double* __restrict__ Rnext, int t)
{
  __shared__ double lds[2*NWAVES];
  const int tid = threadIdx.x;
  const int ln  = tid & 63;
  const int q = swz1024(blockIdx.x);
  const int row0 = q * 4;
  const int b = row0 >> 10;
  const int rr = row0 & (HH-1);
  const int c0 = tid * 2;
  const int base = row0 * WW + c0;
  const bool hasN = (rr > 0);
  const bool hasS = (rr < HH-4);

  F2 pc[4], wgr[4], md[4], rc[4], pHN, pHS, wgN;
  #pragma unroll
  for (int k = 0; k < 4; k++){
    pc[k].v  = *(const float2*)(p + base + k*WW);
    wgr[k].v = *(const float2*)(wg + base + k*WW);
    md[k].v  = *(const float2*)(Md + base + k*WW);
    rc[k].v  = *(const float2*)(r + base + k*WW);
  }
  pHN.v = hasN ? *(const float2*)(p + base - WW)  : zf2();
  wgN.v = hasN ? *(const float2*)(wg + base - WW) : zf2();
  pHS.v = hasS ? *(const float2*)(p + base + 4*WW) : zf2();

  double v1 = (tid < 256) ? Rcur[(b << 8) + tid] : 0.0;
  double v2 = (tid < 256) ? Pcur[(b << 8) + tid] : 0.0;
  block_reduce2(v1, v2, lds);
  const float alpha = (float)(v1 / (v2 + EPS_DOT));

  float pw[4], pe[4], ww[4];
  #pragma unroll
  for (int k = 0; k < 4; k++){
    pw[k] = __shfl_up(pc[k].a[1], 1, 64);
    pe[k] = __shfl_down(pc[k].a[0], 1, 64);
    ww[k] = __shfl_up(wgr[k].a[1], 1, 64);
  }
  if (ln == 0 && c0 > 0){
    #pragma unroll
    for (int k = 0; k < 4; k++){
      pw[k] = p[base + k*WW - 1];
      ww[k] = wg[base + k*WW - 1];
    }
  }
  if (ln == 63 && c0 + 2 < WW){
    #pragma unroll
    for (int k = 0; k < 4; k++) pe[k] = p[base + k*WW + 2];
  }

  double rz_acc = 0.0;
  #pragma unroll
  for (int k = 0; k < 4; k++){
    const float pa[4]  = {pw[k], pc[k].a[0], pc[k].a[1], pe[k]};
    const float wv3[3] = {ww[k], wgr[k].a[0], wgr[k].a[1]};
    F2 ro;
    #pragma unroll
    for (int j = 0; j < 2; j++){
      const int c = c0 + j;
      const float cE = (c < WW-1) ? wv3[j+1] : 0.f;
      const float cW = (c > 0)    ? wv3[j]   : 0.f;
      const float cS = (k < 3) ? wgr[k].a[j] : (hasS ? wgr[3].a[j] : 0.f);
      const float cN = (k > 0) ? wgr[k-1].a[j] : (hasN ? wgN.a[j] : 0.f);
      const float pS = (k < 3) ? pc[k+1].a[j] : pHS.a[j];
      const float pN = (k > 0) ? pc[k-1].a[j] : pHN.a[j];
      const float ap = md[k].a[j]*pa[j+1] - cE*pa[j+2] - cW*pa[j] - cS*pS - cN*pN;
      const float rn = rc[k].a[j] - alpha * ap;
      ro.a[j] = rn;
      rz_acc += (double)rn * (double)(rn / (md[k].a[j] + EPS_PC));
    }
    *(float2*)(r + base + k*WW) = ro.v;
  }
  {
    const double s = block_reduce(rz_acc, lds);
    if (tid == 0) Rnext[q] = s;
  }

  // deferred x-update (t==0: fresh write, no read)
  #pragma unroll
  for (int k = 0; k < 4; k++){
    F2 xo;
    if (t > 0){
      F2 xc; xc.v = *(const float2*)(x + base + k*WW);
      #pragma unroll
      for (int j = 0; j < 2; j++) xo.a[j] = xc.a[j] + alpha * pc[k].a[j];
    } else {
      #pragma unroll
      for (int j = 0; j < 2; j++) xo.a[j] = alpha * pc[k].a[j];
    }
    *(float2*)(x + base + k*WW) = xo.v;
  }
}

// ---- K_X: final update x += alpha_{NIT-1} * p_{NIT-1} ----
__global__ void __launch_bounds__(NT, 8) k_X(
  float* __restrict__ x, const float* __restrict__ p,
  const double* __restrict__ Rcur, const double* __restrict__ Pcur)
{
  __shared__ double lds[2*NWAVES];
  const int tid = threadIdx.x;
  const int q = swz1024(blockIdx.x);
  const int row0 = q * 4;
  const int b = row0 >> 10;
  const int c0 = tid * 2;
  const int base = row0 * WW + c0;

  F2 pc[4], xc[4];
  #pragma unroll
  for (int k = 0; k < 4; k++){
    pc[k].v = *(const float2*)(p + base + k*WW);
    xc[k].v = *(const float2*)(x + base + k*WW);
  }
  double v1 = (tid < 256) ? Rcur[(b << 8) + tid] : 0.0;
  double v2 = (tid < 256) ? Pcur[(b << 8) + tid] : 0.0;
  block_reduce2(v1, v2, lds);
  const float alpha = (float)(v1 / (v2 + EPS_DOT));

  #pragma unroll
  for (int k = 0; k < 4; k++){
    F2 xo;
    #pragma unroll
    for (int j = 0; j < 2; j++) xo.a[j] = xc[k].a[j] + alpha * pc[k].a[j];
    *(float2*)(x + base + k*WW) = xo.v;
  }
}

extern "C" void kernel_launch(void* const* d_in, const int* in_sizes, int n_in,
                              void* d_out, int out_size, void* d_ws, size_t ws_size,
                              hipStream_t stream)
{
  (void)in_sizes; (void)n_in; (void)out_size; (void)ws_size;
  const float* E   = (const float*)d_in[0];
  const float* DL  = (const float*)d_in[1];
  const float* Mm  = (const float*)d_in[2];
  const float* lam = (const float*)d_in[3];
  const float* mu  = (const float*)d_in[4];
  const float* wg  = (const float*)d_in[5];
  float* x = (float*)d_out;

  const int N = BB*HH*WW;
  float* r  = (float*)d_ws;
  float* p0 = r  + N;
  float* p1 = p0 + N;
  float* Md = p1 + N;
  double* R0 = (double*)(Md + N);      // rz rotation [3][NQUAD]
  double* R1 = R0 + NQUAD;
  double* R2 = R1 + NQUAD;
  double* P0 = R2 + NQUAD;             // pAp ping-pong [2][NQUAD]
  double* P1 = P0 + NQUAD;

  double* R[3] = { R0, R1, R2 };
  double* P[2] = { P0, P1 };

  // rz_0 -> R[0]
  k_setup<<<NQUAD, NT, 0, stream>>>(E, DL, Mm, lam, mu, wg, r, p0, Md, R0);

  for (int t = 0; t < NIT; t++){
    float* p_cur = (t & 1) ? p1 : p0;                          // p_t
    const float* p_in = (t == 0) ? p0 : ((t & 1) ? p0 : p1);   // p_{t-1}
    // k_A(t): beta_t from rz_{t-1}=R[(t+2)%3], rz_t=R[t%3]; writes pAp_t->P[t&1]
    k_A<<<NQUAD, NT, 0, stream>>>(r, Md, p_in, p_cur, wg,
                                  R[(t+2)%3], R[t%3], P[t&1], t);
    if (t < NIT-1)
      // k_B(t): alpha_t from (R[t%3], P[t&1]); r update; rz_{t+1}->R[(t+1)%3];
      //         x += alpha_t p_t
      k_B<<<NQUAD, NT, 0, stream>>>(r, p_cur, wg, Md, x,
                                    R[t%3], P[t&1], R[(t+1)%3], t);
  }
  // final x-update with alpha_{12} from (R[12%3], P[12&1]); p_12 = p0
  k_X<<<NQUAD, NT, 0, stream>>>(x, (NIT-1) & 1 ? p1 : p0, R[(NIT-1)%3], P[(NIT-1)&1]);
}

// Round 4
// 548.063 us; speedup vs baseline: 1.2045x; 1.2045x over previous
//
#include <hip/hip_runtime.h>

// Screened Poisson Jacobi-PCG, B=4, H=W=1024, fp32, fixed 13 iterations.
// Multi-kernel CG (proven round-0 structure), float4 everywhere (round-3
// lesson: never trade access width for occupancy).
//   k_A : 1024 blocks x 256 thr, 4 rows/block (BW-heavy; small halo ratio),
//         x-update removed, p_new in place -> lb(256,3).
//   k_B/k_X/k_setup : 2048 blocks x 256 thr, 2 rows/block (latency-bound;
//         2x waves at same float4 width, +10% halo traffic).
// Deferred x lives in k_B (holds p_t and alpha_t anyway).
// Partials: uniform 2048-slot format, 512 slots/batch; 4-row k_A emulates by
// writing slot 2q and zeroing 2q+1. All reductions double => alpha/beta match
// the verified trajectory to ~1e-15.

#define HH 1024
#define WW 1024
#define BB 4
#define NQUAD 1024         // 4096 rows / 4  (k_A grid)
#define NPAIR 2048         // 4096 rows / 2  (setup/k_B/k_X grid)
#define NT 256
#define NWAVES (NT/64)     // 4
#define EPS_PC 1e-8f
#define EPS_DOT 1e-12
#define NIT 13

union F4 { float4 v; float a[4]; };
__device__ __forceinline__ float4 zf4(){ return make_float4(0.f,0.f,0.f,0.f); }

__device__ __forceinline__ double block_reduce(double v, double* lds){
  __syncthreads();
  #pragma unroll
  for (int o = 32; o > 0; o >>= 1) v += __shfl_down(v, o, 64);
  if ((threadIdx.x & 63) == 0) lds[threadIdx.x >> 6] = v;
  __syncthreads();
  if (threadIdx.x == 0){
    double s = lds[0];
    #pragma unroll
    for (int w = 1; w < NWAVES; w++) s += lds[w];
    lds[0] = s;
  }
  __syncthreads();
  return lds[0];
}

__device__ __forceinline__ void block_reduce2(double& v1, double& v2, double* lds){
  __syncthreads();
  #pragma unroll
  for (int o = 32; o > 0; o >>= 1){
    v1 += __shfl_down(v1, o, 64);
    v2 += __shfl_down(v2, o, 64);
  }
  if ((threadIdx.x & 63) == 0){
    lds[threadIdx.x >> 6] = v1;
    lds[NWAVES + (threadIdx.x >> 6)] = v2;
  }
  __syncthreads();
  if (threadIdx.x == 0){
    double s1 = lds[0], s2 = lds[NWAVES];
    #pragma unroll
    for (int w = 1; w < NWAVES; w++){ s1 += lds[w]; s2 += lds[NWAVES + w]; }
    lds[0] = s1; lds[NWAVES] = s2;
  }
  __syncthreads();
  v1 = lds[0]; v2 = lds[NWAVES];
}

// XCD-contiguous swizzles (bijective). Both map XCD k to the SAME contiguous
// 512-row band, so L2 locality is preserved across the mixed-geometry kernels.
__device__ __forceinline__ int swz1024(int bid){ return ((bid & 7) << 7) + (bid >> 3); }
__device__ __forceinline__ int swz2048(int bid){ return ((bid & 7) << 8) + (bid >> 3); }

// ---- setup: b, Mdiag; r=b, p0=z=b/(Md+eps); rz0 partials (2-row blocks) ----
__global__ void __launch_bounds__(NT, 8) k_setup(
  const float* __restrict__ E, const float* __restrict__ DLp,
  const float* __restrict__ Mm, const float* __restrict__ lam,
  const float* __restrict__ mu, const float* __restrict__ wg,
  float* __restrict__ r, float* __restrict__ p0, float* __restrict__ Md,
  double* __restrict__ rz_parts)
{
  __shared__ double lds[2*NWAVES];
  const int tid = threadIdx.x;
  const int ln  = tid & 63;
  const int qq = swz2048(blockIdx.x);
  const int row0 = qq * 2;
  const int rr = row0 & (HH-1);
  const int c0 = tid * 4;
  const int base = row0 * WW + c0;
  const bool hasN = (rr > 0);
  const bool hasS = (rr < HH-2);

  F4 Em1, E0, wm1, w0;
  Em1.v = hasN ? *(const float4*)(E + base - WW)  : zf4();
  wm1.v = hasN ? *(const float4*)(wg + base - WW) : zf4();
  E0.v  = *(const float4*)(E + base);
  w0.v  = *(const float4*)(wg + base);

  double rz_acc = 0.0;
  #pragma unroll
  for (int k = 0; k < 2; k++){
    const int bk = base + k*WW;
    F4 Ep1, wp1, M4, L4, U4, D4;
    Ep1.v = (k < 1 || hasS) ? *(const float4*)(E + bk + WW) : zf4();
    wp1.v = (k < 1) ? *(const float4*)(wg + bk + WW) : zf4();
    M4.v = *(const float4*)(Mm + bk);
    L4.v = *(const float4*)(lam + bk);
    U4.v = *(const float4*)(mu + bk);
    D4.v = *(const float4*)(DLp + bk);

    float Ew  = __shfl_up(E0.a[3], 1, 64);
    float Ee  = __shfl_down(E0.a[0], 1, 64);
    float ww_ = __shfl_up(w0.a[3], 1, 64);
    if (ln == 0 && c0 > 0){ Ew = E[bk-1]; ww_ = wg[bk-1]; }
    if (ln == 63 && c0 + 4 < WW){ Ee = E[bk+4]; }

    const float ev[6]  = {Ew, E0.a[0], E0.a[1], E0.a[2], E0.a[3], Ee};
    const float wv5[5] = {ww_, w0.a[0], w0.a[1], w0.a[2], w0.a[3]};
    const bool rowHasN = (k > 0) || hasN;
    const bool rowHasS = (k < 1) || hasS;

    F4 r4, p4, m4;
    #pragma unroll
    for (int j = 0; j < 4; j++){
      const int c = c0 + j;
      const float cE = (c < WW-1) ? wv5[j+1] : 0.f;
      const float cW = (c > 0)    ? wv5[j]   : 0.f;
      const float cS = rowHasS ? wv5[j+1] : 0.f;
      const float cN = rowHasN ? wm1.a[j] : 0.f;
      const float u  = ev[j+1];
      const float me = U4.a[j] * M4.a[j];
      const float bv = cE*(ev[j+2]-u) - cW*(u-ev[j]) + cS*(Ep1.a[j]-u) - cN*(u-Em1.a[j])
                     + L4.a[j]*u + me*D4.a[j];
      const float mdv = L4.a[j] + me + cE + cW + cS + cN;
      const float z  = bv / (mdv + EPS_PC);
      r4.a[j] = bv; p4.a[j] = z; m4.a[j] = mdv;
      rz_acc += (double)bv * (double)z;
    }
    *(float4*)(r + bk)  = r4.v;
    *(float4*)(p0 + bk) = p4.v;
    *(float4*)(Md + bk) = m4.v;

    Em1 = E0; E0 = Ep1; wm1 = w0; w0 = wp1;   // shift window
  }
  const double s = block_reduce(rz_acc, lds);
  if (tid == 0) rz_parts[qq] = s;
}

// ---- K_A(t): t==0: pAp_0 partials only.
//      t>=1: beta_t; p_t = r/(Md+eps) + beta*p_{t-1} (+halo recompute);
//            pAp_t partials. 4-row blocks; no x traffic. ----
__global__ void __launch_bounds__(NT, 3) k_A(
  const float* __restrict__ r, const float* __restrict__ Md,
  const float* __restrict__ p_in, float* __restrict__ p_out,
  const float* __restrict__ wg,
  const double* __restrict__ Rprev, const double* __restrict__ Rcur,
  double* __restrict__ Pout, int t)
{
  __shared__ double lds[2*NWAVES];
  const int tid = threadIdx.x;
  const int ln  = tid & 63;
  const int q = swz1024(blockIdx.x);
  const int row0 = q * 4;
  const int b = row0 >> 10;
  const int rr = row0 & (HH-1);
  const int c0 = tid * 4;
  const int base = row0 * WW + c0;
  const bool hasN = (rr > 0);
  const bool hasS = (rr < HH-4);

  F4 wgr[4], md[4], wgN;
  #pragma unroll
  for (int k = 0; k < 4; k++){
    wgr[k].v = *(const float4*)(wg + base + k*WW);
    md[k].v  = *(const float4*)(Md + base + k*WW);
  }
  wgN.v = hasN ? *(const float4*)(wg + base - WW) : zf4();

  float pn[6][4];                        // p_new rows rr-1 .. rr+4
  float beta = 0.f;
  if (t == 0){
    F4 tN, tS, tc[4];
    tN.v = hasN ? *(const float4*)(p_in + base - WW) : zf4();
    #pragma unroll
    for (int k = 0; k < 4; k++) tc[k].v = *(const float4*)(p_in + base + k*WW);
    tS.v = hasS ? *(const float4*)(p_in + base + 4*WW) : zf4();
    #pragma unroll
    for (int j = 0; j < 4; j++){
      pn[0][j] = tN.a[j]; pn[5][j] = tS.a[j];
      #pragma unroll
      for (int k = 0; k < 4; k++) pn[k+1][j] = tc[k].a[j];
    }
  } else {
    F4 rcN, pcN, mN, rcS, pcS, mS, rc[4], pc[4];
    if (hasN){
      rcN.v = *(const float4*)(r + base - WW);
      pcN.v = *(const float4*)(p_in + base - WW);
      mN.v  = *(const float4*)(Md + base - WW);
    } else { rcN.v = zf4(); pcN.v = zf4(); mN.v = zf4(); }
    #pragma unroll
    for (int k = 0; k < 4; k++){
      rc[k].v = *(const float4*)(r + base + k*WW);
      pc[k].v = *(const float4*)(p_in + base + k*WW);
    }
    if (hasS){
      rcS.v = *(const float4*)(r + base + 4*WW);
      pcS.v = *(const float4*)(p_in + base + 4*WW);
      mS.v  = *(const float4*)(Md + base + 4*WW);
    } else { rcS.v = zf4(); pcS.v = zf4(); mS.v = zf4(); }

    double v1 = Rprev[(b << 9) + tid] + Rprev[(b << 9) + 256 + tid];
    double v2 = Rcur [(b << 9) + tid] + Rcur [(b << 9) + 256 + tid];
    block_reduce2(v1, v2, lds);
    beta = (float)(v2 / (v1 + EPS_DOT));

    #pragma unroll
    for (int j = 0; j < 4; j++){
      pn[0][j] = hasN ? (rcN.a[j] / (mN.a[j] + EPS_PC) + beta * pcN.a[j]) : 0.f;
      pn[5][j] = hasS ? (rcS.a[j] / (mS.a[j] + EPS_PC) + beta * pcS.a[j]) : 0.f;
      #pragma unroll
      for (int k = 0; k < 4; k++)
        pn[k+1][j] = rc[k].a[j] / (md[k].a[j] + EPS_PC) + beta * pc[k].a[j];
    }
    #pragma unroll
    for (int k = 0; k < 4; k++){
      F4 o;
      #pragma unroll
      for (int j = 0; j < 4; j++) o.a[j] = pn[k+1][j];
      *(float4*)(p_out + base + k*WW) = o.v;
    }
  }

  // west/east exchange via shfl; wave-seam lanes recompute from global
  float pw[4], pe[4], ww[4];
  #pragma unroll
  for (int k = 0; k < 4; k++){
    pw[k] = __shfl_up(pn[k+1][3], 1, 64);
    pe[k] = __shfl_down(pn[k+1][0], 1, 64);
    ww[k] = __shfl_up(wgr[k].a[3], 1, 64);
  }
  if (ln == 0 && c0 > 0){
    #pragma unroll
    for (int k = 0; k < 4; k++){
      const int bk = base + k*WW;
      pw[k] = (t == 0) ? p_in[bk-1]
                       : r[bk-1] / (Md[bk-1] + EPS_PC) + beta * p_in[bk-1];
      ww[k] = wg[bk-1];
    }
  }
  if (ln == 63 && c0 + 4 < WW){
    #pragma unroll
    for (int k = 0; k < 4; k++){
      const int bk = base + k*WW;
      pe[k] = (t == 0) ? p_in[bk+4]
                       : r[bk+4] / (Md[bk+4] + EPS_PC) + beta * p_in[bk+4];
    }
  }

  double acc = 0.0;
  #pragma unroll
  for (int k = 0; k < 4; k++){
    const float pa[6]  = {pw[k], pn[k+1][0], pn[k+1][1], pn[k+1][2], pn[k+1][3], pe[k]};
    const float wv5[5] = {ww[k], wgr[k].a[0], wgr[k].a[1], wgr[k].a[2], wgr[k].a[3]};
    #pragma unroll
    for (int j = 0; j < 4; j++){
      const int c = c0 + j;
      const float cE = (c < WW-1) ? wv5[j+1] : 0.f;
      const float cW = (c > 0)    ? wv5[j]   : 0.f;
      const float cS = (k < 3) ? wgr[k].a[j] : (hasS ? wgr[3].a[j] : 0.f);
      const float cN = (k > 0) ? wgr[k-1].a[j] : (hasN ? wgN.a[j] : 0.f);
      const float ap = md[k].a[j]*pa[j+1] - cE*pa[j+2] - cW*pa[j]
                     - cS*pn[k+2][j] - cN*pn[k][j];
      acc += (double)ap * (double)pa[j+1];
    }
  }
  const double s = block_reduce(acc, lds);
  if (tid == 0){ Pout[2*q] = s; Pout[2*q+1] = 0.0; }
}

// ---- K_B(t), t=0..NIT-2: alpha_t; r -= alpha_t*(A p_t); rz_{t+1} partials;
//      deferred x: x += alpha_t * p_t (t==0: fresh write). 2-row blocks. ----
__global__ void __launch_bounds__(NT, 4) k_B(
  float* __restrict__ r, const float* __restrict__ p,
  const float* __restrict__ wg, const float* __restrict__ Md,
  float* __restrict__ x,
  const double* __restrict__ Rcur, const double* __restrict__ Pcur,
  double* __restrict__ Rnext, int t)
{
  __shared__ double lds[2*NWAVES];
  const int tid = threadIdx.x;
  const int ln  = tid & 63;
  const int qq = swz2048(blockIdx.x);
  const int row0 = qq * 2;
  const int b = row0 >> 10;
  const int rr = row0 & (HH-1);
  const int c0 = tid * 4;
  const int base = row0 * WW + c0;
  const bool hasN = (rr > 0);
  const bool hasS = (rr < HH-2);

  F4 pc[2], wgr[2], md[2], rc[2], pHN, pHS, wgN;
  #pragma unroll
  for (int k = 0; k < 2; k++){
    pc[k].v  = *(const float4*)(p + base + k*WW);
    wgr[k].v = *(const float4*)(wg + base + k*WW);
    md[k].v  = *(const float4*)(Md + base + k*WW);
    rc[k].v  = *(const float4*)(r + base + k*WW);
  }
  pHN.v = hasN ? *(const float4*)(p + base - WW)  : zf4();
  wgN.v = hasN ? *(const float4*)(wg + base - WW) : zf4();
  pHS.v = hasS ? *(const float4*)(p + base + 2*WW) : zf4();

  double v1 = Rcur[(b << 9) + tid] + Rcur[(b << 9) + 256 + tid];
  double v2 = Pcur[(b << 9) + tid] + Pcur[(b << 9) + 256 + tid];
  block_reduce2(v1, v2, lds);
  const float alpha = (float)(v1 / (v2 + EPS_DOT));

  float pw[2], pe[2], ww[2];
  #pragma unroll
  for (int k = 0; k < 2; k++){
    pw[k] = __shfl_up(pc[k].a[3], 1, 64);
    pe[k] = __shfl_down(pc[k].a[0], 1, 64);
    ww[k] = __shfl_up(wgr[k].a[3], 1, 64);
  }
  if (ln == 0 && c0 > 0){
    #pragma unroll
    for (int k = 0; k < 2; k++){
      pw[k] = p[base + k*WW - 1];
      ww[k] = wg[base + k*WW - 1];
    }
  }
  if (ln == 63 && c0 + 4 < WW){
    #pragma unroll
    for (int k = 0; k < 2; k++) pe[k] = p[base + k*WW + 4];
  }

  double rz_acc = 0.0;
  #pragma unroll
  for (int k = 0; k < 2; k++){
    const float pa[6]  = {pw[k], pc[k].a[0], pc[k].a[1], pc[k].a[2], pc[k].a[3], pe[k]};
    const float wv5[5] = {ww[k], wgr[k].a[0], wgr[k].a[1], wgr[k].a[2], wgr[k].a[3]};
    F4 ro;
    #pragma unroll
    for (int j = 0; j < 4; j++){
      const int c = c0 + j;
      const float cE = (c < WW-1) ? wv5[j+1] : 0.f;
      const float cW = (c > 0)    ? wv5[j]   : 0.f;
      const float cS = ((k < 1) || hasS) ? wgr[k].a[j] : 0.f;
      const float cN = (k > 0) ? wgr[k-1].a[j] : (hasN ? wgN.a[j] : 0.f);
      const float pS = (k < 1) ? pc[k+1].a[j] : pHS.a[j];
      const float pN = (k > 0) ? pc[k-1].a[j] : pHN.a[j];
      const float ap = md[k].a[j]*pa[j+1] - cE*pa[j+2] - cW*pa[j] - cS*pS - cN*pN;
      const float rn = rc[k].a[j] - alpha * ap;
      ro.a[j] = rn;
      rz_acc += (double)rn * (double)(rn / (md[k].a[j] + EPS_PC));
    }
    *(float4*)(r + base + k*WW) = ro.v;
  }
  {
    const double s = block_reduce(rz_acc, lds);
    if (tid == 0) Rnext[qq] = s;
  }

  // deferred x-update (t==0: fresh write, no read)
  #pragma unroll
  for (int k = 0; k < 2; k++){
    F4 xo;
    if (t > 0){
      F4 xc; xc.v = *(const float4*)(x + base + k*WW);
      #pragma unroll
      for (int j = 0; j < 4; j++) xo.a[j] = xc.a[j] + alpha * pc[k].a[j];
    } else {
      #pragma unroll
      for (int j = 0; j < 4; j++) xo.a[j] = alpha * pc[k].a[j];
    }
    *(float4*)(x + base + k*WW) = xo.v;
  }
}

// ---- K_X: final update x += alpha_{NIT-1} * p_{NIT-1} (2-row blocks) ----
__global__ void __launch_bounds__(NT, 8) k_X(
  float* __restrict__ x, const float* __restrict__ p,
  const double* __restrict__ Rcur, const double* __restrict__ Pcur)
{
  __shared__ double lds[2*NWAVES];
  const int tid = threadIdx.x;
  const int qq = swz2048(blockIdx.x);
  const int row0 = qq * 2;
  const int b = row0 >> 10;
  const int c0 = tid * 4;
  const int base = row0 * WW + c0;

  F4 pc[2], xc[2];
  #pragma unroll
  for (int k = 0; k < 2; k++){
    pc[k].v = *(const float4*)(p + base + k*WW);
    xc[k].v = *(const float4*)(x + base + k*WW);
  }
  double v1 = Rcur[(b << 9) + tid] + Rcur[(b << 9) + 256 + tid];
  double v2 = Pcur[(b << 9) + tid] + Pcur[(b << 9) + 256 + tid];
  block_reduce2(v1, v2, lds);
  const float alpha = (float)(v1 / (v2 + EPS_DOT));

  #pragma unroll
  for (int k = 0; k < 2; k++){
    F4 xo;
    #pragma unroll
    for (int j = 0; j < 4; j++) xo.a[j] = xc[k].a[j] + alpha * pc[k].a[j];
    *(float4*)(x + base + k*WW) = xo.v;
  }
}

extern "C" void kernel_launch(void* const* d_in, const int* in_sizes, int n_in,
                              void* d_out, int out_size, void* d_ws, size_t ws_size,
                              hipStream_t stream)
{
  (void)in_sizes; (void)n_in; (void)out_size; (void)ws_size;
  const float* E   = (const float*)d_in[0];
  const float* DL  = (const float*)d_in[1];
  const float* Mm  = (const float*)d_in[2];
  const float* lam = (const float*)d_in[3];
  const float* mu  = (const float*)d_in[4];
  const float* wg  = (const float*)d_in[5];
  float* x = (float*)d_out;

  const int N = BB*HH*WW;
  float* r  = (float*)d_ws;
  float* p0 = r  + N;
  float* p1 = p0 + N;
  float* Md = p1 + N;
  double* R0 = (double*)(Md + N);      // rz rotation [3][NPAIR]
  double* R1 = R0 + NPAIR;
  double* R2 = R1 + NPAIR;
  double* P0 = R2 + NPAIR;             // pAp ping-pong [2][NPAIR]
  double* P1 = P0 + NPAIR;

  double* R[3] = { R0, R1, R2 };
  double* P[2] = { P0, P1 };

  // rz_0 -> R[0]
  k_setup<<<NPAIR, NT, 0, stream>>>(E, DL, Mm, lam, mu, wg, r, p0, Md, R0);

  for (int t = 0; t < NIT; t++){
    float* p_cur = (t & 1) ? p1 : p0;                          // p_t
    const float* p_in = (t == 0) ? p0 : ((t & 1) ? p0 : p1);   // p_{t-1}
    // k_A(t): beta_t from rz_{t-1}=R[(t+2)%3], rz_t=R[t%3]; writes pAp_t->P[t&1]
    k_A<<<NQUAD, NT, 0, stream>>>(r, Md, p_in, p_cur, wg,
                                  R[(t+2)%3], R[t%3], P[t&1], t);
    if (t < NIT-1)
      // k_B(t): alpha_t from (R[t%3], P[t&1]); r update; rz_{t+1}->R[(t+1)%3];
      //         x += alpha_t p_t
      k_B<<<NPAIR, NT, 0, stream>>>(r, p_cur, wg, Md, x,
                                    R[t%3], P[t&1], R[(t+1)%3], t);
  }
  // final x-update with alpha_{12} from (R[12%3], P[12&1]); p_12 = p0
  k_X<<<NPAIR, NT, 0, stream>>>(x, (NIT-1) & 1 ? p1 : p0, R[(NIT-1)%3], P[(NIT-1)&1]);
}